// Round 1
// baseline (500.079 us; speedup 1.0000x reference)
//
#include <hip/hip_runtime.h>
#include <hip/hip_bf16.h>
#include <cstdint>

#define LOGZERO (-1e30f)

typedef unsigned short ushort_t;

constexpr int Tc = 512, Bc = 32, Vc = 4096, Sc = 128;
// trellis length L = 2*Sc + 1 = 257 states

__device__ __forceinline__ float lse2(float a, float b) {
    float m = fmaxf(a, b);
    return m + __logf(__expf(a - m) + __expf(b - m));
}
__device__ __forceinline__ float lse3(float a, float b, float c) {
    float m = fmaxf(fmaxf(a, b), c);
    return m + __logf(__expf(a - m) + __expf(b - m) + __expf(c - m));
}

__device__ __forceinline__ float bflo(uint32_t p) {
    return __uint_as_float(p << 16);
}
__device__ __forceinline__ float bfhi(uint32_t p) {
    return __uint_as_float(p & 0xffff0000u);
}
__device__ __forceinline__ float bfs(ushort_t s) {
    return __uint_as_float(((uint32_t)s) << 16);
}

// ---------------------------------------------------------------------------
// Kernel 1: gather emissions. emitT[b][t][s] = bf16(lp[t,b,targets[b,s]]),
// blankT[b][t] = bf16(lp[t,b,0]). Massive parallelism (T*B blocks) so the
// scattered HBM reads run at full-chip bandwidth.
// ---------------------------------------------------------------------------
__global__ __launch_bounds__(128) void k_gather(const float* __restrict__ lp,
                                                const int* __restrict__ tgt,
                                                ushort_t* __restrict__ emitT,
                                                ushort_t* __restrict__ blankT) {
    const int t = blockIdx.x;
    const int b = blockIdx.y;
    const float* row = lp + ((size_t)t * Bc + b) * Vc;
    const int s = threadIdx.x;            // blockDim.x == Sc == 128
    const int lab = tgt[b * Sc + s];
    float v = row[lab];
    __hip_bfloat16 h = __float2bfloat16(v);
    emitT[((size_t)b * Tc + t) * Sc + s] = *reinterpret_cast<ushort_t*>(&h);
    if (s == 0) {
        __hip_bfloat16 hb = __float2bfloat16(row[0]);
        blankT[(size_t)b * Tc + t] = *reinterpret_cast<ushort_t*>(&hb);
    }
}

// ---------------------------------------------------------------------------
// Kernel 2: CTC alpha recursion. One wave (64 lanes) per batch element.
// Lane l owns states j = 4l..4l+3; state 256 rides in a 5th register (valid
// on lane 63). Only alpha[4l-1] crosses the lane boundary -> one shfl_up.
// Register prefetch pipeline of depth 8 hides the per-step emit load.
// ---------------------------------------------------------------------------
__global__ __launch_bounds__(64) void k_ctc(const ushort_t* __restrict__ emitT,
                                            const ushort_t* __restrict__ blankT,
                                            const int* __restrict__ tgt,
                                            const int* __restrict__ in_len,
                                            const int* __restrict__ tg_len,
                                            float* __restrict__ ll_out) {
    const int b = blockIdx.x;
    const int lane = threadIdx.x;
    const uint32_t* prow = reinterpret_cast<const uint32_t*>(emitT + (size_t)b * Tc * Sc);
    const ushort_t* brow = blankT + (size_t)b * Tc;

    // per-lane skip masks (additive: 0 = skip allowed, LOGZERO = disabled)
    const int tg0 = tgt[b * Sc + 2 * lane];         // label for state 4l+1
    const int tg1 = tgt[b * Sc + 2 * lane + 1];     // label for state 4l+3
    const int tgm = (lane > 0) ? tgt[b * Sc + 2 * lane - 1] : tg0;
    const float m1 = (lane > 0 && tg0 != tgm) ? 0.f : LOGZERO;  // j=4l+1 skip uses alpha[4l-1]
    const float m3 = (tg1 != tg0) ? 0.f : LOGZERO;              // j=4l+3 skip uses alpha[4l+1]

    int len = in_len[b];
    len = min(len, Tc);
    const int steps = len - 1;                  // live update steps t = 1..steps

    // init t = 0: alpha0[0] = emit blank, alpha0[1] = emit tgt[0]
    const uint32_t p0 = prow[lane];
    const float bl0 = bfs(brow[0]);
    float a0 = (lane == 0) ? bl0 : LOGZERO;
    float a1 = (lane == 0) ? bflo(p0) : LOGZERO;
    float a2 = LOGZERO, a3 = LOGZERO, a4 = LOGZERO;

    constexpr int D = 8;                        // prefetch depth
    const int padded = ((steps + D - 1) / D) * D;
    uint32_t pk[D];
    ushort_t bk[D];
#pragma unroll
    for (int d = 0; d < D; ++d) {
        int tt = 1 + d;
        if (tt > steps) tt = (steps > 0) ? steps : 0;
        pk[d] = prow[(size_t)tt * 64 + lane];
        bk[d] = brow[tt];
    }

    int t = 1;
    for (int blk = 0; blk < padded / D; ++blk) {
#pragma unroll
        for (int d = 0; d < D; ++d, ++t) {
            const float e1 = bflo(pk[d]);       // emit for state 4l+1
            const float e3 = bfhi(pk[d]);       // emit for state 4l+3
            const float ebl = bfs(bk[d]);       // emit for even states (blank)

            // refill stage d with step t+D (clamped); loads retire D iters later
            int tn = t + D;
            if (tn > steps) tn = steps;
            pk[d] = prow[(size_t)tn * 64 + lane];
            bk[d] = brow[tn];

            float sh = __shfl_up(a3, 1);        // alpha_old[4l-1]
            if (lane == 0) sh = LOGZERO;

            const float n0 = ebl + lse2(a0, sh);
            const float n1 = e1 + lse3(a1, a0, sh + m1);
            const float n2 = ebl + lse2(a2, a1);
            const float n3 = e3 + lse3(a3, a2, a1 + m3);
            const float n4 = ebl + lse2(a4, a3);  // state 256 (lane 63's a3 = state 255)

            const bool live = (t <= steps);
            a0 = live ? n0 : a0;
            a1 = live ? n1 : a1;
            a2 = live ? n2 : a2;
            a3 = live ? n3 : a3;
            a4 = live ? n4 : a4;
        }
    }

    // terminal: ll = logaddexp(alpha[2*tl], alpha[2*tl-1])
    __shared__ float sa[264];
    sa[4 * lane + 0] = a0;
    sa[4 * lane + 1] = a1;
    sa[4 * lane + 2] = a2;
    sa[4 * lane + 3] = a3;
    if (lane == 63) sa[256] = a4;
    __syncthreads();
    if (lane == 0) {
        const int tl = tg_len[b];
        const int e = 2 * tl;
        const float ll = lse2(sa[e], sa[e - 1]);
        ll_out[b] = ll / (float)tl / (float)Bc;
    }
}

// ---------------------------------------------------------------------------
// Kernel 3: reduce the 32 per-batch terms into the scalar output.
// ---------------------------------------------------------------------------
__global__ __launch_bounds__(64) void k_final(const float* __restrict__ ll,
                                              float* __restrict__ out) {
    float v = (threadIdx.x < Bc) ? ll[threadIdx.x] : 0.f;
#pragma unroll
    for (int o = 32; o > 0; o >>= 1) v += __shfl_down(v, o);
    if (threadIdx.x == 0) out[0] = v;
}

extern "C" void kernel_launch(void* const* d_in, const int* in_sizes, int n_in,
                              void* d_out, int out_size, void* d_ws, size_t ws_size,
                              hipStream_t stream) {
    const float* lp = (const float*)d_in[0];       // (T,B,V) fp32 log-softmax
    const int* tgt = (const int*)d_in[1];          // (B,S) int32
    const int* in_len = (const int*)d_in[2];       // (B,)
    const int* tg_len = (const int*)d_in[3];       // (B,)

    char* ws = (char*)d_ws;
    float* ll = (float*)ws;                                   // 32 floats
    ushort_t* blankT = (ushort_t*)(ws + 256);                 // B*T bf16 = 32 KB
    ushort_t* emitT = (ushort_t*)(ws + 256 + 32 * 1024);      // B*T*S bf16 = 4 MB

    k_gather<<<dim3(Tc, Bc), 128, 0, stream>>>(lp, tgt, emitT, blankT);
    k_ctc<<<Bc, 64, 0, stream>>>(emitT, blankT, tgt, in_len, tg_len, ll);
    k_final<<<1, 64, 0, stream>>>(ll, (float*)d_out);
}

// Round 3
// 384.212 us; speedup vs baseline: 1.3016x; 1.3016x over previous
//
#include <hip/hip_runtime.h>
#include <hip/hip_bf16.h>
#include <cstdint>

typedef unsigned short u16;
typedef uint32_t u32;

constexpr int Tc = 512, Bc = 32, Vc = 4096, Sc = 128;
constexpr int BOOST = 13;   // per-step 2^13 boost folded into emissions (exactly accounted)
constexpr int DPF = 16;     // prefetch depth in steps
constexpr float LOG2E = 1.4426950408889634f;
constexpr float LN2 = 0.6931471805599453f;

__device__ __forceinline__ float bfs(u32 s) { return __uint_as_float(s << 16); }
__device__ __forceinline__ float bflo(u32 p) { return __uint_as_float(p << 16); }
__device__ __forceinline__ float bfhi(u32 p) { return __uint_as_float(p & 0xffff0000u); }

__device__ __forceinline__ u16 f2bf(float f) {
    __hip_bfloat16 h = __float2bfloat16(f);
    return *reinterpret_cast<u16*>(&h);
}

// ---------------------------------------------------------------------------
// Kernel 1: gather + exponentiate emissions.
// emitT[b][t][s] = bf16( 2^13 * p[t,b,targets[b,s]] ),  blankT likewise for blank.
// ---------------------------------------------------------------------------
__global__ __launch_bounds__(128) void k_gather(const float* __restrict__ lp,
                                                const int* __restrict__ tgt,
                                                u16* __restrict__ emitT,
                                                u16* __restrict__ blankT) {
    const int t = blockIdx.x;
    const int b = blockIdx.y;
    const float* row = lp + ((size_t)t * Bc + b) * Vc;
    const int s = threadIdx.x;                    // blockDim.x == Sc
    const int lab = tgt[b * Sc + s];
    const float e = __builtin_amdgcn_exp2f(fmaf(row[lab], LOG2E, (float)BOOST));
    emitT[((size_t)b * Tc + t) * Sc + s] = f2bf(e);
    if (s == 0) {
        const float eb = __builtin_amdgcn_exp2f(fmaf(row[0], LOG2E, (float)BOOST));
        blankT[(size_t)b * Tc + t] = f2bf(eb);
    }
}

// ---------------------------------------------------------------------------
// DPP wave-max (64 lanes) -> broadcast via readlane 63.
// ---------------------------------------------------------------------------
template <int CTRL, int RMASK>
__device__ __forceinline__ float dppmax(float v) {
    int t = __builtin_amdgcn_update_dpp(__float_as_int(v), __float_as_int(v),
                                        CTRL, RMASK, 0xf, false);
    return fmaxf(v, __int_as_float(t));
}
__device__ __forceinline__ float wave_max_bcast(float v) {
    v = dppmax<0x111, 0xf>(v);   // row_shr:1
    v = dppmax<0x112, 0xf>(v);   // row_shr:2
    v = dppmax<0x114, 0xf>(v);   // row_shr:4
    v = dppmax<0x118, 0xf>(v);   // row_shr:8
    v = dppmax<0x142, 0xa>(v);   // row_bcast:15 -> rows 1,3
    v = dppmax<0x143, 0xc>(v);   // row_bcast:31 -> rows 2,3
    return __int_as_float(__builtin_amdgcn_readlane(__float_as_int(v), 63));
}

// ---------------------------------------------------------------------------
// Kernel 2: linear-domain CTC alpha recursion, one wave per batch element.
// Lane l owns states 4l..4l+3; state 256 rides in a4 (live on lane 63 only).
// Renormalize by an exact power of 2 every 8 steps (DPP wave-max).
// ---------------------------------------------------------------------------
__global__ __launch_bounds__(64) void k_ctc(const u16* __restrict__ emitT,
                                            const u16* __restrict__ blankT,
                                            const int* __restrict__ tgt,
                                            const int* __restrict__ in_len,
                                            const int* __restrict__ tg_len,
                                            float* __restrict__ out) {
    const int b = blockIdx.x;
    const int lane = threadIdx.x;
    const u32* prow = reinterpret_cast<const u32*>(emitT + (size_t)b * Tc * Sc);
    const u16* brow = blankT + (size_t)b * Tc;

    // skip-transition masks (multiplicative 0/1)
    const int tg0 = tgt[b * Sc + 2 * lane];
    const int tg1 = tgt[b * Sc + 2 * lane + 1];
    const int tgm = (lane > 0) ? tgt[b * Sc + 2 * lane - 1] : tg0;
    const float m1 = (lane > 0 && tg0 != tgm) ? 1.f : 0.f;  // j=4l+1 skip via alpha[4l-1]
    const float m3 = (tg1 != tg0) ? 1.f : 0.f;              // j=4l+3 skip via alpha[4l+1]
    const float sel = (lane == 63) ? 1.f : 0.f;             // state 256 gate

    const int steps = min(in_len[b], Tc) - 1;   // live steps: t = 1..steps

    // t = 0 init (values carry one 2^BOOST factor)
    const u32 p0 = prow[lane];
    float a0 = (lane == 0) ? bfs(brow[0]) : 0.f;
    float a1 = (lane == 0) ? bflo(p0) : 0.f;
    float a2 = 0.f, a3 = 0.f, a4 = 0.f;
    int e_acc = 0;

    u32 pk[DPF];
    u32 bk[DPF];
#pragma unroll
    for (int d = 0; d < DPF; ++d) {
        int tt = 1 + d;
        if (tt > steps) tt = (steps > 0) ? steps : 0;
        pk[d] = prow[(size_t)tt * 64 + lane];
        bk[d] = brow[tt];
    }

#define STEP(d) {                                                   \
        const float e1 = bflo(pk[d]);                               \
        const float e3 = bfhi(pk[d]);                               \
        const float ebl = bfs(bk[d]);                               \
        int tn = t + DPF; if (tn > steps) tn = steps;               \
        pk[d] = prow[(size_t)tn * 64 + lane];                       \
        bk[d] = brow[tn];                                           \
        float sh = __shfl_up(a3, 1);                                \
        if (lane == 0) sh = 0.f;                                    \
        const float s01 = a0 + a1;                                  \
        const float s12 = a1 + a2;                                  \
        const float s23 = a2 + a3;                                  \
        const float n0 = ebl * (a0 + sh);                           \
        const float n1 = e1 * fmaf(m1, sh, s01);                    \
        const float n2 = ebl * s12;                                 \
        const float n3 = e3 * fmaf(m3, a1, s23);                    \
        const float n4 = ebl * fmaf(sel, a3, a4);                   \
        const bool live = (t <= steps);                             \
        a0 = live ? n0 : a0; a1 = live ? n1 : a1;                   \
        a2 = live ? n2 : a2; a3 = live ? n3 : a3;                   \
        a4 = live ? n4 : a4;                                        \
        ++t; }

#define RENORM() {                                                  \
        float m = fmaxf(fmaxf(fmaxf(a0, a1), fmaxf(a2, a3)), a4);   \
        m = wave_max_bcast(m);                                      \
        int e = (int)((__float_as_uint(m) >> 23) & 0xffu) - 127;    \
        float scale = __uint_as_float((u32)(127 - e) << 23);        \
        a0 *= scale; a1 *= scale; a2 *= scale;                      \
        a3 *= scale; a4 *= scale;                                   \
        e_acc += e; }

    int t = 1;
    const int ngroups = (steps + 7) / 8;
    const int npair = (ngroups + 1) / 2;
    for (int gp = 0; gp < npair; ++gp) {
#pragma unroll
        for (int d = 0; d < 8; ++d) STEP(d)
        RENORM()
#pragma unroll
        for (int d = 8; d < 16; ++d) STEP(d)
        RENORM()
    }
#undef STEP
#undef RENORM

    // terminal: ll = log(alpha[2tl] + alpha[2tl-1]) + ln2*(e_acc - BOOST*(steps+1))
    __shared__ float sa[257];
    sa[4 * lane + 0] = a0;
    sa[4 * lane + 1] = a1;
    sa[4 * lane + 2] = a2;
    sa[4 * lane + 3] = a3;
    if (lane == 63) sa[256] = a4;
    __syncthreads();
    if (lane == 0) {
        const int tl = tg_len[b];
        const int ei = 2 * tl;
        const float ssum = sa[ei] + sa[ei - 1];
        const float ll = __logf(ssum) +
                         LN2 * ((float)e_acc - (float)BOOST * (float)(steps + 1));
        atomicAdd(out, ll / (float)tl / (float)Bc);
    }
}

extern "C" void kernel_launch(void* const* d_in, const int* in_sizes, int n_in,
                              void* d_out, int out_size, void* d_ws, size_t ws_size,
                              hipStream_t stream) {
    const float* lp = (const float*)d_in[0];   // (T,B,V) fp32 log-softmax
    const int* tgt = (const int*)d_in[1];      // (B,S) int32
    const int* in_len = (const int*)d_in[2];   // (B,)
    const int* tg_len = (const int*)d_in[3];   // (B,)

    char* ws = (char*)d_ws;
    u16* blankT = (u16*)ws;                    // B*T bf16 = 32 KB
    u16* emitT = (u16*)(ws + 64 * 1024);       // B*T*S bf16 = 4 MB

    (void)hipMemsetAsync(d_out, 0, sizeof(float), stream);
    k_gather<<<dim3(Tc, Bc), 128, 0, stream>>>(lp, tgt, emitT, blankT);
    k_ctc<<<Bc, 64, 0, stream>>>(emitT, blankT, tgt, in_len, tg_len, (float*)d_out);
}

// Round 4
// 379.671 us; speedup vs baseline: 1.3171x; 1.0120x over previous
//
#include <hip/hip_runtime.h>
#include <hip/hip_bf16.h>
#include <cstdint>

typedef unsigned short u16;
typedef uint32_t u32;

constexpr int Tc = 512, Bc = 32, Vc = 4096, Sc = 128;
constexpr int BOOST = 13;   // per-step 2^13 boost folded into emissions (exactly accounted)
constexpr int DPF = 16;     // prefetch depth in steps
constexpr float LOG2E = 1.4426950408889634f;
constexpr float LN2 = 0.6931471805599453f;

__device__ __forceinline__ float bflo(u32 p) { return __uint_as_float(p << 16); }
__device__ __forceinline__ float bfhi(u32 p) { return __uint_as_float(p & 0xffff0000u); }

__device__ __forceinline__ u16 f2bf(float f) {
    __hip_bfloat16 h = __float2bfloat16(f);
    return *reinterpret_cast<u16*>(&h);
}

// ---------------------------------------------------------------------------
// Kernel 1: stage the full 16 KB vocab row into LDS with coalesced float4
// loads (full HBM BW), then gather the 128 labels from LDS.
// emitT[b][t][s] = bf16(2^13 * p[t,b,tgt[b,s]]), blankT[b][t] = f32 likewise.
// ---------------------------------------------------------------------------
__global__ __launch_bounds__(256) void k_gather(const float* __restrict__ lp,
                                                const int* __restrict__ tgt,
                                                u16* __restrict__ emitT,
                                                float* __restrict__ blankT) {
    __shared__ float row[Vc];
    const int t = blockIdx.x;
    const int b = blockIdx.y;
    const float4* src4 = reinterpret_cast<const float4*>(lp + ((size_t)t * Bc + b) * Vc);
    float4* row4 = reinterpret_cast<float4*>(row);
#pragma unroll
    for (int i = 0; i < Vc / 4 / 256; ++i)           // 4 iterations
        row4[threadIdx.x + i * 256] = src4[threadIdx.x + i * 256];
    __syncthreads();
    const int s = threadIdx.x;
    if (s < Sc) {
        const int lab = tgt[b * Sc + s];
        const float e = __builtin_amdgcn_exp2f(fmaf(row[lab], LOG2E, (float)BOOST));
        emitT[((size_t)b * Tc + t) * Sc + s] = f2bf(e);
    }
    if (s == 0) {
        blankT[(size_t)b * Tc + t] =
            __builtin_amdgcn_exp2f(fmaf(row[0], LOG2E, (float)BOOST));
    }
}

// ---------------------------------------------------------------------------
// DPP wave-max (64 lanes) -> broadcast via readlane 63.
// ---------------------------------------------------------------------------
template <int CTRL, int RMASK>
__device__ __forceinline__ float dppmax(float v) {
    int t = __builtin_amdgcn_update_dpp(__float_as_int(v), __float_as_int(v),
                                        CTRL, RMASK, 0xf, false);
    return fmaxf(v, __int_as_float(t));
}
__device__ __forceinline__ float wave_max_bcast(float v) {
    v = dppmax<0x111, 0xf>(v);   // row_shr:1
    v = dppmax<0x112, 0xf>(v);   // row_shr:2
    v = dppmax<0x114, 0xf>(v);   // row_shr:4
    v = dppmax<0x118, 0xf>(v);   // row_shr:8
    v = dppmax<0x142, 0xa>(v);   // row_bcast:15 -> rows 1,3
    v = dppmax<0x143, 0xc>(v);   // row_bcast:31 -> rows 2,3
    return __int_as_float(__builtin_amdgcn_readlane(__float_as_int(v), 63));
}

// wave-wide shift right by 1 lane; lane 0 receives 0 (bound_ctrl).
__device__ __forceinline__ float wave_shr1(float v) {
    return __int_as_float(__builtin_amdgcn_update_dpp(
        0, __float_as_int(v), 0x138, 0xf, 0xf, true));
}

// ---------------------------------------------------------------------------
// Kernel 2: linear-domain CTC alpha recursion, one wave per batch element.
// Lane l owns states 4l..4l+3; state 256 rides in a4 (live on lane 63 only).
// Renormalize by an exact power of 2 every 8 steps (DPP wave-max).
// Main loop runs unmasked full 16-step groups; masked 16-step tail handles
// the remainder. Prefetch indices are unclamped: overreads land in live ws
// memory and are never consumed.
// ---------------------------------------------------------------------------
__global__ __launch_bounds__(64) void k_ctc(const u16* __restrict__ emitT,
                                            const float* __restrict__ blankT,
                                            const int* __restrict__ tgt,
                                            const int* __restrict__ in_len,
                                            const int* __restrict__ tg_len,
                                            float* __restrict__ out) {
    const int b = blockIdx.x;
    const int lane = threadIdx.x;
    const u32* prow = reinterpret_cast<const u32*>(emitT + (size_t)b * Tc * Sc);
    const float* brow = blankT + (size_t)b * Tc;

    // skip-transition masks (multiplicative 0/1)
    const int tg0 = tgt[b * Sc + 2 * lane];
    const int tg1 = tgt[b * Sc + 2 * lane + 1];
    const int tgm = (lane > 0) ? tgt[b * Sc + 2 * lane - 1] : tg0;
    const float m1 = (lane > 0 && tg0 != tgm) ? 1.f : 0.f;  // j=4l+1 skip via alpha[4l-1]
    const float m3 = (tg1 != tg0) ? 1.f : 0.f;              // j=4l+3 skip via alpha[4l+1]
    const float sel = (lane == 63) ? 1.f : 0.f;             // state 256 gate

    const int steps = min(in_len[b], Tc) - 1;   // live steps: t = 1..steps

    // t = 0 init (values carry one 2^BOOST factor)
    const u32 p0 = prow[lane];
    float a0 = (lane == 0) ? brow[0] : 0.f;
    float a1 = (lane == 0) ? bflo(p0) : 0.f;
    float a2 = 0.f, a3 = 0.f, a4 = 0.f;
    int e_acc = 0;

    u32 pk[DPF];
    float bk[DPF];
#pragma unroll
    for (int d = 0; d < DPF; ++d) {
        pk[d] = prow[(size_t)(1 + d) * 64 + lane];
        bk[d] = brow[1 + d];
    }

#define STEP_N(d) {                                                 \
        const float e1 = bflo(pk[d]);                               \
        const float e3 = bfhi(pk[d]);                               \
        const float ebl = bk[d];                                    \
        pk[d] = prow[(size_t)(t + DPF) * 64 + lane];                \
        bk[d] = brow[t + DPF];                                      \
        const float sh = wave_shr1(a3);                             \
        const float s01 = a0 + a1;                                  \
        const float s12 = a1 + a2;                                  \
        const float s23 = a2 + a3;                                  \
        const float n0 = ebl * (a0 + sh);                           \
        const float n1 = e1 * fmaf(m1, sh, s01);                    \
        const float n3 = e3 * fmaf(m3, a1, s23);                    \
        a4 = ebl * fmaf(sel, a3, a4);                               \
        a0 = n0; a1 = n1; a2 = ebl * s12; a3 = n3;                  \
        ++t; }

#define STEP_T(d) {                                                 \
        const float e1 = bflo(pk[d]);                               \
        const float e3 = bfhi(pk[d]);                               \
        const float ebl = bk[d];                                    \
        const float sh = wave_shr1(a3);                             \
        const float s01 = a0 + a1;                                  \
        const float s12 = a1 + a2;                                  \
        const float s23 = a2 + a3;                                  \
        const float n0 = ebl * (a0 + sh);                           \
        const float n1 = e1 * fmaf(m1, sh, s01);                    \
        const float n2 = ebl * s12;                                 \
        const float n3 = e3 * fmaf(m3, a1, s23);                    \
        const float n4 = ebl * fmaf(sel, a3, a4);                   \
        const bool live = (t <= steps);                             \
        a0 = live ? n0 : a0; a1 = live ? n1 : a1;                   \
        a2 = live ? n2 : a2; a3 = live ? n3 : a3;                   \
        a4 = live ? n4 : a4;                                        \
        ++t; }

#define RENORM() {                                                  \
        float m = fmaxf(fmaxf(fmaxf(a0, a1), fmaxf(a2, a3)), a4);   \
        m = wave_max_bcast(m);                                      \
        int e = (int)((__float_as_uint(m) >> 23) & 0xffu) - 127;    \
        float scale = __uint_as_float((u32)(127 - e) << 23);        \
        a0 *= scale; a1 *= scale; a2 *= scale;                      \
        a3 *= scale; a4 *= scale;                                   \
        e_acc += e; }

    int t = 1;
    const int nfull = steps >> 4;               // full unmasked 16-step groups
    for (int g = 0; g < nfull; ++g) {
#pragma unroll
        for (int d = 0; d < 8; ++d) STEP_N(d)
        RENORM()
#pragma unroll
        for (int d = 8; d < 16; ++d) STEP_N(d)
        RENORM()
    }
    // masked tail (<= 16 live steps remain)
#pragma unroll
    for (int d = 0; d < 8; ++d) STEP_T(d)
    RENORM()
#pragma unroll
    for (int d = 8; d < 16; ++d) STEP_T(d)
    RENORM()
#undef STEP_N
#undef STEP_T
#undef RENORM

    // terminal: ll = log(alpha[2tl] + alpha[2tl-1]) + ln2*(e_acc - BOOST*(steps+1))
    __shared__ float sa[257];
    sa[4 * lane + 0] = a0;
    sa[4 * lane + 1] = a1;
    sa[4 * lane + 2] = a2;
    sa[4 * lane + 3] = a3;
    if (lane == 63) sa[256] = a4;
    __syncthreads();
    if (lane == 0) {
        const int tl = tg_len[b];
        const int ei = 2 * tl;
        const float ssum = sa[ei] + sa[ei - 1];
        const float ll = __logf(ssum) +
                         LN2 * ((float)e_acc - (float)BOOST * (float)(steps + 1));
        atomicAdd(out, ll / (float)tl / (float)Bc);
    }
}

extern "C" void kernel_launch(void* const* d_in, const int* in_sizes, int n_in,
                              void* d_out, int out_size, void* d_ws, size_t ws_size,
                              hipStream_t stream) {
    const float* lp = (const float*)d_in[0];   // (T,B,V) fp32 log-softmax
    const int* tgt = (const int*)d_in[1];      // (B,S) int32
    const int* in_len = (const int*)d_in[2];   // (B,)
    const int* tg_len = (const int*)d_in[3];   // (B,)

    char* ws = (char*)d_ws;
    float* blankT = (float*)ws;                // B*T f32 = 64 KB
    u16* emitT = (u16*)(ws + 128 * 1024);      // B*T*S bf16 = 4 MB (+ overread slack)

    (void)hipMemsetAsync(d_out, 0, sizeof(float), stream);
    k_gather<<<dim3(Tc, Bc), 256, 0, stream>>>(lp, tgt, emitT, blankT);
    k_ctc<<<Bc, 64, 0, stream>>>(emitT, blankT, tgt, in_len, tg_len, (float*)d_out);
}

// Round 5
// 373.318 us; speedup vs baseline: 1.3396x; 1.0170x over previous
//
#include <hip/hip_runtime.h>
#include <hip/hip_bf16.h>
#include <cstdint>

typedef unsigned short u16;
typedef uint32_t u32;

constexpr int Tc = 512, Bc = 32, Vc = 4096, Sc = 128;
constexpr int BOOST = 13;   // per-step 2^13 boost folded into emissions (exactly accounted)
constexpr int DPF = 16;     // prefetch depth in steps
constexpr int RSTRIDE = 65; // emit row stride in u32: 64 packed bf16 pairs + 1 f32 blank
constexpr float LOG2E = 1.4426950408889634f;
constexpr float LN2 = 0.6931471805599453f;

__device__ __forceinline__ float bflo(u32 p) { return __uint_as_float(p << 16); }
__device__ __forceinline__ float bfhi(u32 p) { return __uint_as_float(p & 0xffff0000u); }

__device__ __forceinline__ u32 f2bf_bits(float f) {
    __hip_bfloat16 h = __float2bfloat16(f);
    return (u32)(*reinterpret_cast<u16*>(&h));
}

// ---------------------------------------------------------------------------
// Kernel 0: per-batch line dedupe. Labels are constant across t, so compute
// once per b: the sorted list of needed 64B lines (16 floats each) of the
// vocab row, and each label's position in the staged compact buffer.
// ---------------------------------------------------------------------------
__global__ __launch_bounds__(128) void k_prep(const int* __restrict__ tgt,
                                              u16* __restrict__ lines,   // [Bc][160]
                                              u16* __restrict__ pos,     // [Bc][128]
                                              int* __restrict__ nl) {    // [Bc]
    __shared__ unsigned bm[8];        // 256-bit bitmap over 4096/16 lines
    __shared__ u16 wbase[9];
    __shared__ u16 rank[256];
    const int b = blockIdx.x;
    const int s = threadIdx.x;        // 128 threads
    if (s < 8) bm[s] = 0u;
    __syncthreads();
    const int lab = tgt[b * Sc + s];
    const int ln = lab >> 4;
    atomicOr(&bm[ln >> 5], 1u << (ln & 31));
    if (s == 0) atomicOr(&bm[0], 1u);         // blank (label 0) -> line 0
    __syncthreads();
    if (s == 0) {
        int acc = 0;
        for (int w = 0; w < 8; ++w) { wbase[w] = (u16)acc; acc += __popc(bm[w]); }
        wbase[8] = (u16)acc;
        nl[b] = acc;
    }
    __syncthreads();
    for (int l = s; l < 256; l += 128) {
        const unsigned w = bm[l >> 5];
        if (w & (1u << (l & 31))) {
            const int r = wbase[l >> 5] + __popc(w & ((1u << (l & 31)) - 1u));
            lines[b * 160 + r] = (u16)l;
            rank[l] = (u16)r;
        }
    }
    __syncthreads();
    pos[b * Sc + s] = (u16)(rank[ln] * 16 + (lab & 15));
}

// ---------------------------------------------------------------------------
// Kernel 1: line-gather. Per (t,b): load ONLY the needed 64B lines (coalesced
// float4, threads tid..tid+3 cover one line), then gather labels from LDS,
// exponentiate, and write the packed emit row:
//   row[j]  (j<64) = bf16pair( 2^13 p[tgt[2j]], 2^13 p[tgt[2j+1]] )
//   row[64]        = f32( 2^13 p[blank] )
// ---------------------------------------------------------------------------
__global__ __launch_bounds__(256) void k_gather2(const float* __restrict__ lp,
                                                 const u16* __restrict__ lines,
                                                 const u16* __restrict__ pos,
                                                 const int* __restrict__ nl,
                                                 u32* __restrict__ emitT) {
    __shared__ __align__(16) float vals[129 * 16];
    __shared__ u16 lpos[Sc];
    const int t = blockIdx.x;
    const int b = blockIdx.y;
    const int n = nl[b];
    const float* row = lp + ((size_t)t * Bc + b) * Vc;
    const int tid = threadIdx.x;
    for (int c = tid; c < n * 4; c += 256) {          // <= 3 iterations
        const int line = (int)lines[b * 160 + (c >> 2)];
        const float4 v = *reinterpret_cast<const float4*>(row + line * 16 + (c & 3) * 4);
        *reinterpret_cast<float4*>(&vals[c * 4]) = v;
    }
    if (tid < Sc) lpos[tid] = pos[b * Sc + tid];
    __syncthreads();
    u32* orow = emitT + ((size_t)b * Tc + t) * RSTRIDE;
    if (tid < 64) {
        const float e0 = __builtin_amdgcn_exp2f(fmaf(vals[lpos[2 * tid]], LOG2E, (float)BOOST));
        const float e1 = __builtin_amdgcn_exp2f(fmaf(vals[lpos[2 * tid + 1]], LOG2E, (float)BOOST));
        orow[tid] = f2bf_bits(e0) | (f2bf_bits(e1) << 16);
    } else if (tid == 64) {
        orow[64] = __float_as_uint(
            __builtin_amdgcn_exp2f(fmaf(vals[0], LOG2E, (float)BOOST)));
    }
}

// ---------------------------------------------------------------------------
// DPP wave-max (64 lanes) -> broadcast via readlane 63.
// ---------------------------------------------------------------------------
template <int CTRL, int RMASK>
__device__ __forceinline__ float dppmax(float v) {
    int t = __builtin_amdgcn_update_dpp(__float_as_int(v), __float_as_int(v),
                                        CTRL, RMASK, 0xf, false);
    return fmaxf(v, __int_as_float(t));
}
__device__ __forceinline__ float wave_max_bcast(float v) {
    v = dppmax<0x111, 0xf>(v);   // row_shr:1
    v = dppmax<0x112, 0xf>(v);   // row_shr:2
    v = dppmax<0x114, 0xf>(v);   // row_shr:4
    v = dppmax<0x118, 0xf>(v);   // row_shr:8
    v = dppmax<0x142, 0xa>(v);   // row_bcast:15 -> rows 1,3
    v = dppmax<0x143, 0xc>(v);   // row_bcast:31 -> rows 2,3
    return __int_as_float(__builtin_amdgcn_readlane(__float_as_int(v), 63));
}

// wave-wide shift right by 1 lane; lane 0 receives 0 (bound_ctrl).
__device__ __forceinline__ float wave_shr1(float v) {
    return __int_as_float(__builtin_amdgcn_update_dpp(
        0, __float_as_int(v), 0x138, 0xf, 0xf, true));
}

// ---------------------------------------------------------------------------
// Kernel 2: linear-domain CTC alpha recursion, one wave per batch element.
// Lane l owns states 4l..4l+3; state 256 rides in a4 (live on lane 63 only).
// Renormalize by an exact power of 2 every 8 steps (DPP wave-max).
// Marching group pointer + immediate offsets: no per-step 64-bit addr math.
// ---------------------------------------------------------------------------
__global__ __launch_bounds__(64) void k_ctc(const u32* __restrict__ emitT,
                                            const int* __restrict__ tgt,
                                            const int* __restrict__ in_len,
                                            const int* __restrict__ tg_len,
                                            float* __restrict__ out) {
    const int b = blockIdx.x;
    const int lane = threadIdx.x;
    const u32* p = emitT + (size_t)b * Tc * RSTRIDE;

    // skip-transition masks (multiplicative 0/1)
    const int tg0 = tgt[b * Sc + 2 * lane];
    const int tg1 = tgt[b * Sc + 2 * lane + 1];
    const int tgm = (lane > 0) ? tgt[b * Sc + 2 * lane - 1] : tg0;
    const float m1 = (lane > 0 && tg0 != tgm) ? 1.f : 0.f;  // j=4l+1 skip via alpha[4l-1]
    const float m3 = (tg1 != tg0) ? 1.f : 0.f;              // j=4l+3 skip via alpha[4l+1]
    const float sel = (lane == 63) ? 1.f : 0.f;             // state 256 gate

    const int steps = min(in_len[b], Tc) - 1;   // live steps: t = 1..steps

    // t = 0 init (values carry one 2^BOOST factor)
    const u32 p0 = p[lane];
    float a0 = (lane == 0) ? __uint_as_float(p[64]) : 0.f;
    float a1 = (lane == 0) ? bflo(p0) : 0.f;
    float a2 = 0.f, a3 = 0.f, a4 = 0.f;
    int e_acc = 0;

    u32 pk[DPF];
    float bk[DPF];
    const u32* pr = p + RSTRIDE;                // row t=1
#pragma unroll
    for (int d = 0; d < DPF; ++d) {
        pk[d] = pr[d * RSTRIDE + lane];
        bk[d] = __uint_as_float(pr[d * RSTRIDE + 64]);
    }
    const u32* pg = p + (size_t)(DPF + 1) * RSTRIDE;  // refill source for group 0

#define STEP_N(d) {                                                 \
        const float e1 = bflo(pk[d]);                               \
        const float e3 = bfhi(pk[d]);                               \
        const float ebl = bk[d];                                    \
        pk[d] = pg[(d) * RSTRIDE + lane];                           \
        bk[d] = __uint_as_float(pg[(d) * RSTRIDE + 64]);            \
        const float sh = wave_shr1(a3);                             \
        const float s01 = a0 + a1;                                  \
        const float s12 = a1 + a2;                                  \
        const float s23 = a2 + a3;                                  \
        const float n0 = ebl * (a0 + sh);                           \
        const float n1 = e1 * fmaf(m1, sh, s01);                    \
        const float n3 = e3 * fmaf(m3, a1, s23);                    \
        a4 = ebl * fmaf(sel, a3, a4);                               \
        a0 = n0; a1 = n1; a2 = ebl * s12; a3 = n3;                  }

#define STEP_T(d) {                                                 \
        const float e1 = bflo(pk[d]);                               \
        const float e3 = bfhi(pk[d]);                               \
        const float ebl = bk[d];                                    \
        const float sh = wave_shr1(a3);                             \
        const float s01 = a0 + a1;                                  \
        const float s12 = a1 + a2;                                  \
        const float s23 = a2 + a3;                                  \
        const float n0 = ebl * (a0 + sh);                           \
        const float n1 = e1 * fmaf(m1, sh, s01);                    \
        const float n2 = ebl * s12;                                 \
        const float n3 = e3 * fmaf(m3, a1, s23);                    \
        const float n4 = ebl * fmaf(sel, a3, a4);                   \
        const bool live = (t <= steps);                             \
        a0 = live ? n0 : a0; a1 = live ? n1 : a1;                   \
        a2 = live ? n2 : a2; a3 = live ? n3 : a3;                   \
        a4 = live ? n4 : a4;                                        \
        ++t; }

#define RENORM() {                                                  \
        float m = fmaxf(fmaxf(fmaxf(a0, a1), fmaxf(a2, a3)), a4);   \
        m = wave_max_bcast(m);                                      \
        int e = (int)((__float_as_uint(m) >> 23) & 0xffu) - 127;    \
        float scale = __uint_as_float((u32)(127 - e) << 23);        \
        a0 *= scale; a1 *= scale; a2 *= scale;                      \
        a3 *= scale; a4 *= scale;                                   \
        e_acc += e; }

    const int nfull = steps >> 4;               // full unmasked 16-step groups
    for (int g = 0; g < nfull; ++g) {
#pragma unroll
        for (int d = 0; d < 8; ++d) STEP_N(d)
        RENORM()
#pragma unroll
        for (int d = 8; d < 16; ++d) STEP_N(d)
        RENORM()
        pg += DPF * RSTRIDE;
    }
    // masked tail (<= 16 live steps remain)
    int t = nfull * 16 + 1;
#pragma unroll
    for (int d = 0; d < 8; ++d) STEP_T(d)
    RENORM()
#pragma unroll
    for (int d = 8; d < 16; ++d) STEP_T(d)
    RENORM()
#undef STEP_N
#undef STEP_T
#undef RENORM

    // terminal: ll = log(alpha[2tl] + alpha[2tl-1]) + ln2*(e_acc - BOOST*(steps+1))
    __shared__ float sa[257];
    sa[4 * lane + 0] = a0;
    sa[4 * lane + 1] = a1;
    sa[4 * lane + 2] = a2;
    sa[4 * lane + 3] = a3;
    if (lane == 63) sa[256] = a4;
    __syncthreads();
    if (lane == 0) {
        const int tl = tg_len[b];
        const int ei = 2 * tl;
        const float ssum = sa[ei] + sa[ei - 1];
        const float ll = __logf(ssum) +
                         LN2 * ((float)e_acc - (float)BOOST * (float)(steps + 1));
        atomicAdd(out, ll / (float)tl / (float)Bc);
    }
}

extern "C" void kernel_launch(void* const* d_in, const int* in_sizes, int n_in,
                              void* d_out, int out_size, void* d_ws, size_t ws_size,
                              hipStream_t stream) {
    const float* lp = (const float*)d_in[0];   // (T,B,V) fp32 log-softmax
    const int* tgt = (const int*)d_in[1];      // (B,S) int32
    const int* in_len = (const int*)d_in[2];   // (B,)
    const int* tg_len = (const int*)d_in[3];   // (B,)

    char* ws = (char*)d_ws;
    int* nl = (int*)ws;                        // 32 ints           @ 0
    u16* lines = (u16*)(ws + 256);             // 32*160 u16        @ 256
    u16* pos = (u16*)(ws + 16 * 1024);         // 32*128 u16        @ 16K
    u32* emitT = (u32*)(ws + 32 * 1024);       // 32*512*65 u32 ~ 4.1 MB (+1 row overread slack)

    (void)hipMemsetAsync(d_out, 0, sizeof(float), stream);
    k_prep<<<Bc, 128, 0, stream>>>(tgt, lines, pos, nl);
    k_gather2<<<dim3(Tc, Bc), 256, 0, stream>>>(lp, lines, pos, nl, emitT);
    k_ctc<<<Bc, 64, 0, stream>>>(emitT, tgt, in_len, tg_len, (float*)d_out);
}

// Round 6
// 364.191 us; speedup vs baseline: 1.3731x; 1.0251x over previous
//
#include <hip/hip_runtime.h>
#include <hip/hip_bf16.h>
#include <cstdint>

typedef unsigned short u16;
typedef uint32_t u32;

constexpr int Tc = 512, Bc = 32, Vc = 4096, Sc = 128;
constexpr int BOOST = 13;    // per-step 2^13 boost folded into emissions (exactly accounted)
constexpr int BSTRIDE = 576; // blankT row stride (Tc + 64 slack)
constexpr float LOG2E = 1.4426950408889634f;
constexpr float LN2 = 0.6931471805599453f;

__device__ __forceinline__ float bflo(u32 p) { return __uint_as_float(p << 16); }
__device__ __forceinline__ float bfhi(u32 p) { return __uint_as_float(p & 0xffff0000u); }

__device__ __forceinline__ u32 f2bf_bits(float f) {
    __hip_bfloat16 h = __float2bfloat16(f);
    return (u32)(*reinterpret_cast<u16*>(&h));
}

// readlane -> SGPR float (lane index is a compile-time constant after unroll)
#define RLF(v, i) __int_as_float(__builtin_amdgcn_readlane(__float_as_int(v), (i)))

// ---------------------------------------------------------------------------
// Kernel 1: fused dedupe + line-gather. Per (t,b) block: rebuild the per-b
// line list (labels constant over t; ~400 cyc), load ONLY the needed 64B
// lines coalesced, exponentiate, write the packed 256B emit row:
//   row[j] (j<64) = bf16pair( 2^13 p[tgt[2j]], 2^13 p[tgt[2j+1]] )
// and blankT[b][t] = f32( 2^13 p[blank] ).
// ---------------------------------------------------------------------------
__global__ __launch_bounds__(256) void k_gather(const float* __restrict__ lp,
                                                const int* __restrict__ tgt,
                                                u32* __restrict__ emitT,
                                                float* __restrict__ blankT) {
    __shared__ u32 bm[8];             // bitmap over 256 lines of 16 floats
    __shared__ u16 wbase[8];
    __shared__ int sn;
    __shared__ u16 rank[256];
    __shared__ u16 slines[136];
    __shared__ u16 lpos[Sc];
    __shared__ __align__(16) float vals[130 * 16];

    const int t = blockIdx.x;
    const int b = blockIdx.y;
    const int tid = threadIdx.x;

    if (tid < 8) bm[tid] = (tid == 0) ? 1u : 0u;   // blank -> line 0 preset
    __syncthreads();
    int lab = 0;
    if (tid < Sc) {
        lab = tgt[b * Sc + tid];
        const int ln = lab >> 4;
        atomicOr(&bm[ln >> 5], 1u << (ln & 31));
    }
    __syncthreads();
    if (tid == 0) {
        int acc = 0;
        for (int w = 0; w < 8; ++w) { wbase[w] = (u16)acc; acc += __popc(bm[w]); }
        sn = acc;
    }
    __syncthreads();
    {   // rank/scatter: one thread per candidate line
        const u32 w = bm[tid >> 5];
        if (w & (1u << (tid & 31))) {
            const int r = wbase[tid >> 5] + __popc(w & ((1u << (tid & 31)) - 1u));
            slines[r] = (u16)tid;
            rank[tid] = (u16)r;
        }
    }
    __syncthreads();
    if (tid < Sc) lpos[tid] = (u16)(rank[lab >> 4] * 16 + (lab & 15));
    const int n = sn;
    const float* row = lp + ((size_t)t * Bc + b) * Vc;
    for (int c = tid; c < n * 4; c += 256) {       // threads c..: 16B chunk of a line
        const int line = (int)slines[c >> 2];
        *reinterpret_cast<float4*>(&vals[c * 4]) =
            *reinterpret_cast<const float4*>(row + line * 16 + (c & 3) * 4);
    }
    __syncthreads();
    u32* orow = emitT + ((size_t)b * Tc + t) * 64;
    if (tid < 64) {
        const float e0 = __builtin_amdgcn_exp2f(fmaf(vals[lpos[2 * tid]], LOG2E, (float)BOOST));
        const float e1 = __builtin_amdgcn_exp2f(fmaf(vals[lpos[2 * tid + 1]], LOG2E, (float)BOOST));
        orow[tid] = f2bf_bits(e0) | (f2bf_bits(e1) << 16);
    } else if (tid == 64) {
        blankT[b * BSTRIDE + t] =
            __builtin_amdgcn_exp2f(fmaf(vals[0], LOG2E, (float)BOOST));
    }
}

// ---------------------------------------------------------------------------
// DPP wave-max (64 lanes) -> broadcast via readlane 63.
// ---------------------------------------------------------------------------
template <int CTRL, int RMASK>
__device__ __forceinline__ float dppmax(float v) {
    int t = __builtin_amdgcn_update_dpp(__float_as_int(v), __float_as_int(v),
                                        CTRL, RMASK, 0xf, false);
    return fmaxf(v, __int_as_float(t));
}
__device__ __forceinline__ float wave_max_bcast(float v) {
    v = dppmax<0x111, 0xf>(v);   // row_shr:1
    v = dppmax<0x112, 0xf>(v);   // row_shr:2
    v = dppmax<0x114, 0xf>(v);   // row_shr:4
    v = dppmax<0x118, 0xf>(v);   // row_shr:8
    v = dppmax<0x142, 0xa>(v);   // row_bcast:15 -> rows 1,3
    v = dppmax<0x143, 0xc>(v);   // row_bcast:31 -> rows 2,3
    return __int_as_float(__builtin_amdgcn_readlane(__float_as_int(v), 63));
}

// wave-wide shift right by 1 lane; lane 0 receives 0 (bound_ctrl).
__device__ __forceinline__ float wave_shr1(float v) {
    return __int_as_float(__builtin_amdgcn_update_dpp(
        0, __float_as_int(v), 0x138, 0xf, 0xf, true));
}

// ---------------------------------------------------------------------------
// Kernel 2: linear-domain CTC alpha recursion, one wave per batch element.
// Lane l owns states 4l..4l+3; state 256 rides in a4 (lane 63). Blank stream:
// ONE lane-coalesced vector load per 64 steps + per-step v_readlane (no
// wave-uniform scalar loads -> no lgkmcnt(0)-per-step drain). Emit stream:
// 32-row-deep register prefetch (slot (t-1)&31, refill row t+32).
// Renormalize by an exact power of 2 every 8 steps.
// ---------------------------------------------------------------------------
__global__ __launch_bounds__(64) void k_ctc(const u32* __restrict__ emitT,
                                            const float* __restrict__ blankT,
                                            const int* __restrict__ tgt,
                                            const int* __restrict__ in_len,
                                            const int* __restrict__ tg_len,
                                            float* __restrict__ out) {
    const int b = blockIdx.x;
    const int lane = threadIdx.x;
    const u32* p = emitT + (size_t)b * Tc * 64;
    const float* brow = blankT + b * BSTRIDE;

    // skip-transition masks (multiplicative 0/1)
    const int tg0 = tgt[b * Sc + 2 * lane];
    const int tg1 = tgt[b * Sc + 2 * lane + 1];
    const int tgm = (lane > 0) ? tgt[b * Sc + 2 * lane - 1] : tg0;
    const float m1 = (lane > 0 && tg0 != tgm) ? 1.f : 0.f;  // j=4l+1 skip via alpha[4l-1]
    const float m3 = (tg1 != tg0) ? 1.f : 0.f;              // j=4l+3 skip via alpha[4l+1]
    const float sel = (lane == 63) ? 1.f : 0.f;             // state 256 gate

    const int steps = min(in_len[b], Tc) - 1;   // live steps: t = 1..steps

    // t = 0 init (values carry one 2^BOOST factor)
    const u32 p0 = p[lane];
    float a0 = (lane == 0) ? brow[0] : 0.f;
    float a1 = (lane == 0) ? bflo(p0) : 0.f;
    float a2 = 0.f, a3 = 0.f, a4 = 0.f;
    int e_acc = 0;

    u32 pk[32];
    const u32* pr = p + 64;                     // row t=1
#pragma unroll
    for (int d = 0; d < 32; ++d) pk[d] = pr[d * 64 + lane];
    const u32* pg = p + (size_t)33 * 64;        // refill source: row t+32 for t=1

    float blkc = brow[1 + lane];                // blanks for t = 1..64

#define RENORM() {                                                  \
        float m = fmaxf(fmaxf(fmaxf(a0, a1), fmaxf(a2, a3)), a4);   \
        m = wave_max_bcast(m);                                      \
        int e = (int)((__float_as_uint(m) >> 23) & 0xffu) - 127;    \
        float scale = __uint_as_float((u32)(127 - e) << 23);        \
        a0 *= scale; a1 *= scale; a2 *= scale;                      \
        a3 *= scale; a4 *= scale;                                   \
        e_acc += e; }

    // unmasked 16-step group; g = group index within superblock (0..3)
#define GROUP_N(g) {                                                \
        const int H = ((g) & 1) * 16;                               \
        const int BI = (g) * 16;                                    \
        _Pragma("unroll")                                           \
        for (int d = 0; d < 16; ++d) {                              \
            const u32 pv = pk[H + d];                               \
            pk[H + d] = pg[d * 64 + lane];                          \
            const float ebl = RLF(blkc, BI + d);                    \
            const float e1 = bflo(pv);                              \
            const float e3 = bfhi(pv);                              \
            const float sh = wave_shr1(a3);                         \
            const float s01 = a0 + a1;                              \
            const float s12 = a1 + a2;                              \
            const float s23 = a2 + a3;                              \
            const float n0 = ebl * (a0 + sh);                       \
            const float n1 = e1 * fmaf(m1, sh, s01);                \
            const float n3 = e3 * fmaf(m3, a1, s23);                \
            a4 = ebl * fmaf(sel, a3, a4);                           \
            a0 = n0; a1 = n1; a2 = ebl * s12; a3 = n3;              \
            if (d == 7 || d == 15) RENORM()                         \
        }                                                           \
        pg += 16 * 64; }

    // masked 16-step group (tail superblock)
#define GROUP_T(g) {                                                \
        const int H = ((g) & 1) * 16;                               \
        const int BI = (g) * 16;                                    \
        _Pragma("unroll")                                           \
        for (int d = 0; d < 16; ++d) {                              \
            const u32 pv = pk[H + d];                               \
            pk[H + d] = pg[d * 64 + lane];                          \
            const float ebl = RLF(blkc, BI + d);                    \
            const float e1 = bflo(pv);                              \
            const float e3 = bfhi(pv);                              \
            const float sh = wave_shr1(a3);                         \
            const float s01 = a0 + a1;                              \
            const float s12 = a1 + a2;                              \
            const float s23 = a2 + a3;                              \
            const float n0 = ebl * (a0 + sh);                       \
            const float n1 = e1 * fmaf(m1, sh, s01);                \
            const float n2 = ebl * s12;                             \
            const float n3 = e3 * fmaf(m3, a1, s23);                \
            const float n4 = ebl * fmaf(sel, a3, a4);               \
            const bool live = (t <= steps);                         \
            a0 = live ? n0 : a0; a1 = live ? n1 : a1;               \
            a2 = live ? n2 : a2; a3 = live ? n3 : a3;               \
            a4 = live ? n4 : a4;                                    \
            ++t;                                                    \
            if (d == 7 || d == 15) RENORM()                         \
        }                                                           \
        pg += 16 * 64; }

    const int nsb = steps >> 6;                 // full 64-step superblocks
    for (int sb = 0; sb < nsb; ++sb) {
        const float blkn = brow[(sb + 1) * 64 + 1 + lane];
        GROUP_N(0) GROUP_N(1) GROUP_N(2) GROUP_N(3)
        blkc = blkn;
    }
    // masked tail superblock (<= 64 live steps remain; renorms are
    // value-preserving on frozen alphas via e_acc accounting)
    int t = (nsb << 6) + 1;
    GROUP_T(0) GROUP_T(1) GROUP_T(2) GROUP_T(3)
#undef GROUP_N
#undef GROUP_T
#undef RENORM

    // terminal: ll = log(alpha[2tl] + alpha[2tl-1]) + ln2*(e_acc - BOOST*(steps+1))
    __shared__ float sa[257];
    sa[4 * lane + 0] = a0;
    sa[4 * lane + 1] = a1;
    sa[4 * lane + 2] = a2;
    sa[4 * lane + 3] = a3;
    if (lane == 63) sa[256] = a4;
    __syncthreads();
    if (lane == 0) {
        const int tl = tg_len[b];
        const int ei = 2 * tl;
        const float ssum = sa[ei] + sa[ei - 1];
        const float ll = __logf(ssum) +
                         LN2 * ((float)e_acc - (float)BOOST * (float)(steps + 1));
        atomicAdd(out, ll / (float)tl / (float)Bc);
    }
}

extern "C" void kernel_launch(void* const* d_in, const int* in_sizes, int n_in,
                              void* d_out, int out_size, void* d_ws, size_t ws_size,
                              hipStream_t stream) {
    const float* lp = (const float*)d_in[0];   // (T,B,V) fp32 log-softmax
    const int* tgt = (const int*)d_in[1];      // (B,S) int32
    const int* in_len = (const int*)d_in[2];   // (B,)
    const int* tg_len = (const int*)d_in[3];   // (B,)

    char* ws = (char*)d_ws;
    float* blankT = (float*)ws;                // Bc*BSTRIDE f32 = 72 KB
    u32* emitT = (u32*)(ws + 128 * 1024);      // Bc*Tc*64 u32 = 4 MB (+overread slack in ws)

    (void)hipMemsetAsync(d_out, 0, sizeof(float), stream);
    k_gather<<<dim3(Tc, Bc), 256, 0, stream>>>(lp, tgt, emitT, blankT);
    k_ctc<<<Bc, 64, 0, stream>>>(emitT, blankT, tgt, in_len, tg_len, (float*)d_out);
}